// Round 1
// 121.636 us; speedup vs baseline: 1.0773x; 1.0773x over previous
//
#include <hip/hip_runtime.h>
#include <cstddef>

// Problem constants: (B,W,D,H,C) = (2,16,16,16,32), N = 4096 per batch.
#define NN 4096

typedef short bf16x8 __attribute__((ext_vector_type(8)));
typedef float f32x4 __attribute__((ext_vector_type(4)));
typedef float f32x2 __attribute__((ext_vector_type(2)));

__device__ __forceinline__ unsigned short f2bf(float f) {
    union { float f; unsigned u; } v; v.f = f;
    unsigned r = v.u + 0x7fffu + ((v.u >> 16) & 1u);   // RNE
    return (unsigned short)(r >> 16);
}

// ---------------------------------------------------------------------------
// Kernel A: fused Q/K/J/V projections + M = K.J^T (kB folded in via atomics).
// Outputs: Qf,Kf fp32 [b][r*4096+sp]; Vt bf16 [b][c*4096+sp] (transposed, the
// B-operand layout kD's MFMA wants); Mm[b*64 + r*8 + s] accumulated atomically
// (must be pre-zeroed by a hipMemsetAsync before this kernel).
// Block = 256 threads = 32 spatial points x 8 groups, grid = 256.
// ---------------------------------------------------------------------------
__global__ __launch_bounds__(256) void kA(
    const float* __restrict__ x,
    const float* __restrict__ qw, const float* __restrict__ qb,
    const float* __restrict__ qs, const float* __restrict__ qo,
    const float* __restrict__ kw, const float* __restrict__ kb,
    const float* __restrict__ ks, const float* __restrict__ ko,
    const float* __restrict__ jw, const float* __restrict__ jb,
    const float* __restrict__ js, const float* __restrict__ jo,
    const float* __restrict__ vw, const float* __restrict__ vb,
    const float* __restrict__ vs, const float* __restrict__ vo,
    float* __restrict__ Qf, float* __restrict__ Kf,
    unsigned short* __restrict__ Vt, float* __restrict__ Mm)
{
    __shared__ float vw_s[1024];        // [ci][co]
    __shared__ float cw_s[3 * 776];     // conv weights [conv][tap*256+ci*8+co]
    __shared__ float Kl[32][8];         // this block's K octets
    __shared__ float Jl[32][8];         // this block's J octets
    const int t = threadIdx.x;
    for (int i = t; i < 1024; i += 256) vw_s[i] = vw[i];
    for (int i = t; i < 768; i += 256) {
        cw_s[i]        = qw[i];
        cw_s[776 + i]  = kw[i];
        cw_s[1552 + i] = jw[i];
    }
    __syncthreads();

    const int spi = t >> 3;
    const int gsp = blockIdx.x * 32 + spi;      // b*4096+sp (b uniform per block)
    const int b   = gsp >> 12;
    const int sp  = gsp & 4095;
    const int w = sp >> 8, d = (sp >> 4) & 15, h = sp & 15;
    const float4* xr = (const float4*)(x + (size_t)gsp * 32);

    // ---- V (pointwise 32->32): 4 channels per thread, stored bf16 transposed ----
    {
        const int c4 = t & 7;
        float4 acc = make_float4(0.f, 0.f, 0.f, 0.f);
        #pragma unroll
        for (int c8 = 0; c8 < 8; ++c8) {
            const float4 xv = xr[c8];
            #pragma unroll
            for (int k = 0; k < 4; ++k) {
                const float xs = (k == 0) ? xv.x : (k == 1) ? xv.y : (k == 2) ? xv.z : xv.w;
                const float4 wv = *(const float4*)&vw_s[(c8 * 4 + k) * 32 + c4 * 4];
                acc.x += xs * wv.x; acc.y += xs * wv.y;
                acc.z += xs * wv.z; acc.w += xs * wv.w;
            }
        }
        const float4 bb = ((const float4*)vb)[c4];
        const float4 sc = ((const float4*)vs)[c4];
        const float4 oo = ((const float4*)vo)[c4];
        float4 r;
        r.x = fmaxf((acc.x + bb.x) * sc.x + oo.x, 0.f);
        r.y = fmaxf((acc.y + bb.y) * sc.y + oo.y, 0.f);
        r.z = fmaxf((acc.z + bb.z) * sc.z + oo.z, 0.f);
        r.w = fmaxf((acc.w + bb.w) * sc.w + oo.w, 0.f);
        unsigned short* vt = Vt + (size_t)b * 131072 + (size_t)(c4 * 4) * 4096 + sp;
        vt[0]        = f2bf(r.x);
        vt[4096]     = f2bf(r.y);
        vt[2 * 4096] = f2bf(r.z);
        vt[3 * 4096] = f2bf(r.w);
    }

    // ---- Q/K/J (3-tap 1-D convs along d/w/h): groups g<6 active ----
    {
        const int g = t & 7;
        if (g < 6) {
            const int conv = g >> 1;           // 0=Q(d), 1=K(w), 2=J(h)
            const int co4  = g & 1;
            const int coord  = (conv == 0) ? d : (conv == 1) ? w : h;
            const int stride = (conv == 0) ? 16 : (conv == 1) ? 256 : 1;
            const float* cw = cw_s + conv * 776;
            float4 acc = make_float4(0.f, 0.f, 0.f, 0.f);
            #pragma unroll
            for (int tap = 0; tap < 3; ++tap) {
                const int cc = coord + tap - 1;
                if (cc < 0 || cc > 15) continue;           // SAME zero-pad
                const float4* xt = (const float4*)(x + (size_t)(gsp + (tap - 1) * stride) * 32);
                #pragma unroll
                for (int c8 = 0; c8 < 8; ++c8) {
                    const float4 xv = xt[c8];
                    #pragma unroll
                    for (int k = 0; k < 4; ++k) {
                        const float xs = (k == 0) ? xv.x : (k == 1) ? xv.y : (k == 2) ? xv.z : xv.w;
                        const float4 wv = *(const float4*)&cw[tap * 256 + (c8 * 4 + k) * 8 + co4 * 4];
                        acc.x += xs * wv.x; acc.y += xs * wv.y;
                        acc.z += xs * wv.z; acc.w += xs * wv.w;
                    }
                }
            }
            const float* bbp = (conv == 0) ? qb : (conv == 1) ? kb : jb;
            const float* scp = (conv == 0) ? qs : (conv == 1) ? ks : js;
            const float* oop = (conv == 0) ? qo : (conv == 1) ? ko : jo;
            const float4 bb = ((const float4*)bbp)[co4];
            const float4 sc = ((const float4*)scp)[co4];
            const float4 oo = ((const float4*)oop)[co4];
            float4 r;
            r.x = fmaxf((acc.x + bb.x) * sc.x + oo.x, 0.f);
            r.y = fmaxf((acc.y + bb.y) * sc.y + oo.y, 0.f);
            r.z = fmaxf((acc.z + bb.z) * sc.z + oo.z, 0.f);
            r.w = fmaxf((acc.w + bb.w) * sc.w + oo.w, 0.f);
            if (conv == 0) {
                ((float4*)(Qf + (size_t)b * 32768 + (size_t)sp * 8))[co4] = r;
            } else if (conv == 1) {
                ((float4*)(Kf + (size_t)b * 32768 + (size_t)sp * 8))[co4] = r;
                *(float4*)&Kl[spi][co4 * 4] = r;
            } else {
                *(float4*)&Jl[spi][co4 * 4] = r;
            }
        }
    }

    // ---- M partial: outer products of this block's 32 (K,J) octets ----
    __syncthreads();
    if (t < 64) {
        const int r = t >> 3, s = t & 7;
        float acc = 0.f;
        #pragma unroll 8
        for (int i = 0; i < 32; ++i) acc += Kl[i][r] * Jl[i][s];
        atomicAdd(&Mm[b * 64 + t], acc);
    }
}

// ---------------------------------------------------------------------------
// Kernel D: out[b][i][c] += gamma * sum_{j in split} sigmoid(P_i.Kcol_j)*V[j][c]
// (out pre-initialized to x by a D2D copy.)
// Block: 256 threads = 4 waves, TI=64 rows, j-split of 512 (8 chunks of 64).
// Grid: 2b x 64 rowtiles x 8 jsplits = 1024 blocks.
//
// This revision vs previous:
//  - K chunk (8x512 fp32, 16.5 KB) staged into LDS ONCE, not per-64-chunk.
//  - s_lds double-buffered -> exactly ONE __syncthreads per 64-chunk (was 3).
//    Safety: writer of buf p at chunk jc passed barrier jc-1, which every wave
//    reaches only after its phase-2 reads of buf p (chunk jc-2) drained.
//  - dot over j packed as float2 elementwise-fma (v_pk_fma_f32 candidate).
//  - -log2(e) folded into P (P2) -> sigmoid = rcp(1 + v_exp_f32(dot)).
//  - bf16 pack via single v_cvt_pk_bf16_f32 (RNE, lo=src0) per pair.
//  - B-fragments (global Vt, L2-resident) prefetched at chunk top, consumed
//    after the barrier; phase-1 VALU hides the L2 latency.
//  - s_setprio(1) around the MFMA cluster (T5; phase-split structure exists).
// Verified layouts (m89/m120): A[m=lane&15][k=quad*8+j]; B[k=quad*8+j][n=lane&15];
// C/D: col=lane&15, row=quad*4+reg.
// ---------------------------------------------------------------------------
__global__ __launch_bounds__(256) void kD(
    const float* __restrict__ Qf, const float* __restrict__ Mm,
    const float* __restrict__ Kf, const unsigned short* __restrict__ Vt,
    const float* __restrict__ gamma, float* __restrict__ out)
{
    const int blk = blockIdx.x;
    const int jsp = blk & 7;
    const int rt  = (blk >> 3) & 63;
    const int b   = blk >> 9;
    const int i0  = rt * 64;
    const int j0  = jsp * 512;
    const int t   = threadIdx.x;
    // phase-1 mapping: 16 rowgroups (4 rows) x 16 jgroups (4 j)
    const int jg = t & 15, rg = t >> 4;
    // phase-2 mapping: wave w covers rows w*16..w*16+15
    const int w = t >> 6, lane = t & 63;
    const int m = lane & 15, quad = lane >> 4;

    __shared__ float m_s[64];
    __shared__ float kt_s[8][516];           // whole K chunk [r][j], pad -> 2-way max
    __shared__ unsigned short s_lds[2][64][72]; // sigmoid tile bf16, double-buffered

    const float* Kb = Kf + (size_t)b * 32768;
    const unsigned short* Vb = Vt + (size_t)b * 131072;

    if (t < 64) m_s[t] = Mm[b * 64 + t];
    #pragma unroll
    for (int v = 0; v < 4; ++v) {            // stage 8x512 fp32 K chunk once
        const int idx = t + v * 256;         // 0..1023 float4s
        const int r = idx >> 7, j4 = (idx & 127) << 2;
        *(float4*)&kt_s[r][j4] = *(const float4*)(Kb + (size_t)r * 4096 + j0 + j4);
    }
    __syncthreads();

    // P2[4 rows][8] = -log2(e) * (Q-rows . M)
    float P2[4][8];
    {
        float a[4][8];
        #pragma unroll
        for (int r = 0; r < 8; ++r) {
            const float* qr = Qf + (size_t)b * 32768 + (size_t)r * 4096 + i0 + rg * 4;
            #pragma unroll
            for (int ri = 0; ri < 4; ++ri) a[ri][r] = qr[ri];
        }
        #pragma unroll
        for (int s = 0; s < 8; ++s) {
            #pragma unroll
            for (int ri = 0; ri < 4; ++ri) {
                float acc = 0.f;
                #pragma unroll
                for (int r = 0; r < 8; ++r) acc += a[ri][r] * m_s[r * 8 + s];
                P2[ri][s] = acc * -1.44269504f;
            }
        }
    }

    f32x4 acc0 = {0.f, 0.f, 0.f, 0.f};
    f32x4 acc1 = {0.f, 0.f, 0.f, 0.f};

    #pragma unroll 1
    for (int jc = 0; jc < 8; ++jc) {
        const int jb = j0 + jc * 64;
        // prefetch B frags; the barrier's vmcnt(0) drain is exactly their use site
        const bf16x8 bv00 = *(const bf16x8*)(Vb + (size_t)m * 4096 + jb + quad * 8);
        const bf16x8 bv10 = *(const bf16x8*)(Vb + (size_t)m * 4096 + jb + 32 + quad * 8);
        const bf16x8 bv01 = *(const bf16x8*)(Vb + (size_t)(16 + m) * 4096 + jb + quad * 8);
        const bf16x8 bv11 = *(const bf16x8*)(Vb + (size_t)(16 + m) * 4096 + jb + 32 + quad * 8);

        unsigned short (*sl)[72] = s_lds[jc & 1];

        // phase 1: 16 sigmoids per thread (4 rows x 4 j), bf16 tile to sl
        unsigned hpk[4][2];
        #pragma unroll
        for (int tp = 0; tp < 2; ++tp) {
            const int jcol = jg * 4 + tp * 2;
            f32x2 pa[4];
            #pragma unroll
            for (int ri = 0; ri < 4; ++ri) pa[ri] = (f32x2){0.f, 0.f};
            #pragma unroll
            for (int r = 0; r < 8; ++r) {
                const f32x2 kv = *(const f32x2*)&kt_s[r][jcol];
                #pragma unroll
                for (int ri = 0; ri < 4; ++ri)
                    pa[ri] = __builtin_elementwise_fma((f32x2){P2[ri][r], P2[ri][r]}, kv, pa[ri]);
            }
            #pragma unroll
            for (int ri = 0; ri < 4; ++ri) {
                float e0, e1;
                asm("v_exp_f32 %0, %1" : "=v"(e0) : "v"(pa[ri].x));
                asm("v_exp_f32 %0, %1" : "=v"(e1) : "v"(pa[ri].y));
                const float s0 = __builtin_amdgcn_rcpf(1.0f + e0);
                const float s1 = __builtin_amdgcn_rcpf(1.0f + e1);
                unsigned pk;
                asm("v_cvt_pk_bf16_f32 %0, %1, %2" : "=v"(pk) : "v"(s0), "v"(s1));
                hpk[ri][tp] = pk;
            }
        }
        #pragma unroll
        for (int ri = 0; ri < 4; ++ri)
            *(uint2*)&sl[rg * 4 + ri][jg * 4] = make_uint2(hpk[ri][0], hpk[ri][1]);

        __syncthreads();

        // phase 2: 4 MFMAs per wave (2 k-tiles x 2 n-tiles), B from regs
        __builtin_amdgcn_s_setprio(1);
        const bf16x8 af0 = *(const bf16x8*)&sl[w * 16 + m][quad * 8];
        const bf16x8 af1 = *(const bf16x8*)&sl[w * 16 + m][32 + quad * 8];
        acc0 = __builtin_amdgcn_mfma_f32_16x16x32_bf16(af0, bv00, acc0, 0, 0, 0);
        acc1 = __builtin_amdgcn_mfma_f32_16x16x32_bf16(af0, bv01, acc1, 0, 0, 0);
        acc0 = __builtin_amdgcn_mfma_f32_16x16x32_bf16(af1, bv10, acc0, 0, 0, 0);
        acc1 = __builtin_amdgcn_mfma_f32_16x16x32_bf16(af1, bv11, acc1, 0, 0, 0);
        __builtin_amdgcn_s_setprio(0);
    }

    // epilogue: atomic accumulate gamma-scaled partials onto out (pre-set to x)
    const float g = gamma[0];
    #pragma unroll
    for (int reg = 0; reg < 4; ++reg) {
        const int row = i0 + w * 16 + quad * 4 + reg;
        float* op = out + ((size_t)b * 4096 + row) * 32 + m;
        atomicAdd(op,      g * acc0[reg]);
        atomicAdd(op + 16, g * acc1[reg]);
    }
}

// ---------------------------------------------------------------------------
extern "C" void kernel_launch(void* const* d_in, const int* in_sizes, int n_in,
                              void* d_out, int out_size, void* d_ws, size_t ws_size,
                              hipStream_t stream)
{
    const float* x     = (const float*)d_in[0];
    const float* gamma = (const float*)d_in[1];
    const float* qw = (const float*)d_in[2];
    const float* qb = (const float*)d_in[3];
    const float* qs = (const float*)d_in[4];
    const float* qo = (const float*)d_in[5];
    const float* kw = (const float*)d_in[6];
    const float* kb = (const float*)d_in[7];
    const float* ks = (const float*)d_in[8];
    const float* ko = (const float*)d_in[9];
    const float* jw = (const float*)d_in[10];
    const float* jb = (const float*)d_in[11];
    const float* js = (const float*)d_in[12];
    const float* jo = (const float*)d_in[13];
    const float* vw = (const float*)d_in[14];
    const float* vb = (const float*)d_in[15];
    const float* vs = (const float*)d_in[16];
    const float* vo = (const float*)d_in[17];

    float* ws = (float*)d_ws;
    float* Qf = ws;                                   // 65536 floats
    float* Kf = ws + 65536;                           // 65536
    float* Mm = ws + 131072;                          // 128
    unsigned short* Vt = (unsigned short*)(ws + 131200); // 262144 bf16 (16B-aligned)

    hipMemsetAsync(Mm, 0, 128 * sizeof(float), stream);
    hipMemcpyAsync(d_out, x, (size_t)262144 * sizeof(float),
                   hipMemcpyDeviceToDevice, stream);
    kA<<<256, 256, 0, stream>>>(x, qw, qb, qs, qo, kw, kb, ks, ko,
                                jw, jb, js, jo, vw, vb, vs, vo,
                                Qf, Kf, Vt, Mm);
    kD<<<1024, 256, 0, stream>>>(Qf, Mm, Kf, Vt, gamma, (float*)d_out);
}